// Round 1
// baseline (2141.900 us; speedup 1.0000x reference)
//
#include <hip/hip_runtime.h>
#include <hip/hip_bf16.h>
#include <stdint.h>

#define HD   512   // hidden dim H
#define ID   128   // input dim I
#define NCLS 100   // num classes
#define TT   512   // sequence length T
#define BB   128   // batch B
#define NEMB 101   // NC + 1 embedding rows
#define NGRP 32    // independent batch groups
#define GWG  8     // workgroups per group (sync clique)
#define RPG  4     // batch rows per group
#define COLS 64    // hidden cols per WG (GWG*COLS == HD)
#define THR  1024  // threads per recurrence WG (16 waves, 4 waves/SIMD)
#define CPAD 520   // LDS C row stride (mult of 4 -> float4-aligned; skews banks)
#define PST  5     // partials slot stride in float2 (4 rows + 1 pad)

// workspace layout (bytes)
#define WS_FLAG 0
#define WS_BAR  4096                   // u32 flags[NGRP*GWG*32] (128 B apart)
#define WS_G    65536                  // float G[101][2048]  (808 KB)
#define WS_C0   (1u * 1024 * 1024)     // float C0[128][512]  (256 KB)
#define WS_C1   (WS_C0 + 262144)       // float C1[128][512]  (256 KB)
#define WS_HFB  (WS_C1 + 262144)       // float Hfb[128][512] (256 KB)
#define NBARU   8192                   // u32s to zero (32 KB of flags)

using bf16 = __hip_bfloat16;

__device__ __forceinline__ float b2f(bf16 v) { return __bfloat162float(v); }
__device__ __forceinline__ float sigf(float x) { return 1.0f / (1.0f + expf(-x)); }

// Agent-scope (sc1) accessors — proven r6-r17.
__device__ __forceinline__ float cld(const float* p) {
    return __hip_atomic_load(p, __ATOMIC_RELAXED, __HIP_MEMORY_SCOPE_AGENT);
}
__device__ __forceinline__ void cst(float* p, float v) {
    __hip_atomic_store(p, v, __ATOMIC_RELAXED, __HIP_MEMORY_SCOPE_AGENT);
}
__device__ __forceinline__ unsigned cldu(const unsigned* p) {
    return __hip_atomic_load(p, __ATOMIC_RELAXED, __HIP_MEMORY_SCOPE_AGENT);
}
__device__ __forceinline__ void cstu(unsigned* p, unsigned v) {
    __hip_atomic_store(p, v, __ATOMIC_RELAXED, __HIP_MEMORY_SCOPE_AGENT);
}

template <bool BF>
__device__ __forceinline__ float ldv(const void* p, int i) {
    if constexpr (BF) return b2f(((const bf16*)p)[i]);
    else              return ((const float*)p)[i];
}

// ---------------------------------------------------------------------------
// Dtype sniffer + flags zeroing. emb row 0 is exactly 0.0 by construction:
// bytes [256,512) are zero iff f32 (row 0) and nonzero iff bf16 (row 1).
// ---------------------------------------------------------------------------
__global__ void init_k(const uint32_t* __restrict__ emb_raw,
                       int* __restrict__ flag, unsigned* __restrict__ bars) {
    const int t = threadIdx.x;
    for (int k = t; k < NBARU; k += 1024) bars[k] = 0u;
    if (t == 0) {
        uint32_t acc = 0;
        for (int i = 64; i < 128; ++i) acc |= emb_raw[i];
        *flag = (acc == 0u) ? 0 : 1;
    }
}

// ---------------------------------------------------------------------------
// G[c][j]: input-side gate pre-activations per class. j = q*512 + col,
// q in {0:f, 1:i, 2:o, 3:ctilde}; ctilde quarter pre-sigmoided.
// ---------------------------------------------------------------------------
template <bool BF>
__global__ void build_G(const int* __restrict__ flag,
                        const void* __restrict__ emb,
                        const void* __restrict__ Wfx, const void* __restrict__ Wix,
                        const void* __restrict__ Wox, const void* __restrict__ Wcx,
                        const void* __restrict__ bfv, const void* __restrict__ biv,
                        const void* __restrict__ bov, const void* __restrict__ bcv,
                        float* __restrict__ G) {
    if (*flag != (BF ? 1 : 0)) return;
    const int c   = blockIdx.x;
    const int j   = blockIdx.y * 256 + threadIdx.x;
    const int q   = j >> 9;
    const int col = j & 511;
    const void* W  = (q == 0) ? Wfx : (q == 1) ? Wix : (q == 2) ? Wox : Wcx;
    const void* bv = (q == 0) ? bfv : (q == 1) ? biv : (q == 2) ? bov : bcv;
    float acc = ldv<BF>(bv, col);
    for (int i = 0; i < ID; ++i)
        acc += ldv<BF>(emb, c * ID + i) * ldv<BF>(W, i * HD + col);
    if (q == 3) acc = sigf(acc);
    G[c * 2048 + j] = acc;
}

// ---------------------------------------------------------------------------
// Batch-split recurrence, 32 groups x 8 WGs x 64 cols. NEW exchange scheme
// (this round): the counting barrier + convergence-then-load is replaced by
// per-(rank,row) data-ready flags so the remote-C exchange OVERLAPS the
// local update phase:
//   - dot phase (all 16 waves) reads Cs = C(t-1) from LDS          -> S1
//   - waves 0..3 (updaters, wave w == row w): reduce partials, gates,
//     Cn; coherent-store own 64-col block to the ping-pong buffer; write
//     own slice straight into Cs; per-WAVE s_waitcnt vmcnt(0) drain; lane 0
//     publishes flag[rank][row] = t+1. (Per-wave drain gives the same
//     visibility guarantee the proven syncthreads-before-arrive pattern
//     used — stores are acked at the coherence point before vmcnt hits 0.)
//   - waves 8..15 (stagers, one per remote rank) poll that rank's 4 row
//     flags (monotone counters, >= t+1), then load its 64-col block for all
//     4 rows and write into Cs. Remote flags depend only on REMOTE
//     updaters, so this runs concurrently with our own update.   -> S2
// 2 syncthreads/step (was 4 + RMW barrier + poll). Skew between ranks is
// bounded by 1 step (a rank's stagers need everyone's flag >= t+1 before
// its next update), so the 2-deep C0/C1 ping-pong stays race-free.
// Final step publishes/stages nothing: Cs keeps the carry C(T-2), which is
// exactly what the o-gate epilogue needs (r15 semantics), so the epilogue
// re-stage and the C0/C1 zero-init + startup barrier are gone.
// Dot phase, weight pinning (64 regs, re-pinned in-loop) and all math are
// unchanged — values are bit-identical to the previous version.
// ---------------------------------------------------------------------------
template <bool BF>
__global__ __launch_bounds__(THR, 1) void recur_bs(
    const int* __restrict__ flag, const int* __restrict__ x,
    const float* __restrict__ G,
    const void* __restrict__ Wfc, const void* __restrict__ Wic,
    const void* __restrict__ Woc,
    float* __restrict__ C0, float* __restrict__ C1,
    float* __restrict__ Hfb, unsigned* __restrict__ flags)
{
    if (*flag != (BF ? 1 : 0)) return;

    __shared__ __align__(16) float Cs[RPG * CPAD];        // 8.3 KB
    __shared__ __align__(8)  float2 part2[2048 * PST];    // 80 KB
    __shared__ int idx[RPG * TT];                         // 8 KB
    __shared__ int lz[RPG];

    const int blk   = blockIdx.x;
    const int grp   = blk >> 3;           // 0..31
    const int rank  = blk & 7;            // 0..7
    const int r0    = grp * RPG;
    const int h0    = rank * COLS;
    const int tid   = threadIdx.x;
    const int cp    = tid & 31;           // col pair: cols cp, cp+32
    const int chunk = tid >> 5;           // 0..31 (16 h' each)
    const int sw    = tid >> 6;           // wave id 0..15
    const int sl    = tid & 63;           // lane in wave
    unsigned* myf = flags + (grp * 8 + rank) * 32;   // own 4 row flags (128 B apart)

    // ---- stage x rows (2048 ints), zero Cs, find group start ----
    idx[tid]        = x[r0 * TT + tid];
    idx[tid + 1024] = x[r0 * TT + tid + 1024];
    for (int k = tid; k < RPG * CPAD; k += THR) Cs[k] = 0.0f;
    if (tid < RPG) lz[tid] = -1;
    __syncthreads();
    if (tid < TT)
        #pragma unroll
        for (int r = 0; r < RPG; ++r)
            if (idx[r * TT + tid] == 0) atomicMax(&lz[r], tid);
    __syncthreads();
    int t0 = TT;
    #pragma unroll
    for (int r = 0; r < RPG; ++r) t0 = min(t0, lz[r] + 1);
    // t0 is group-uniform: every WG computes it from the same 4 rows.

    // ---- 64 pinned register weights: 2 cols x 2 gates x own 16-h' chunk --
    float wfA[16], wfB[16], wiA[16], wiB[16];
    #pragma unroll
    for (int k = 0; k < 16; ++k) {
        const int hp = chunk * 16 + k;
        wfA[k] = ldv<BF>(Wfc, hp * HD + h0 + cp);
        wfB[k] = ldv<BF>(Wfc, hp * HD + h0 + cp + 32);
        wiA[k] = ldv<BF>(Wic, hp * HD + h0 + cp);
        wiB[k] = ldv<BF>(Wic, hp * HD + h0 + cp + 32);
    }
    #pragma unroll
    for (int k = 0; k < 16; ++k)
        asm volatile("" : "+v"(wfA[k]), "+v"(wfB[k]), "+v"(wiA[k]), "+v"(wiB[k]));

    float Creg = 0.0f;                    // update threads' own C element
    const bool isUpd = (tid < COLS * RPG);
    const int uc = tid & 63, ur = tid >> 6;   // update thread's (col, row)

    for (int t = t0; t < TT; ++t) {
        // re-pin the weights every iteration (r7/r8/r10 lesson: pre-loop pin
        // alone was not enough — allocator spilled after the asm point).
        #pragma unroll
        for (int k = 0; k < 16; ++k)
            asm volatile("" : "+v"(wfA[k]), "+v"(wfB[k]), "+v"(wiA[k]), "+v"(wiB[k]));

        float* pub = (t & 1) ? C1 : C0;       // where C(t) gets published
        const bool lastStep = (t == TT - 1);

        // ---- prefetch G gate operands for the update (hides under the dot)
        float gf = 0.f, gi = 0.f, sgc = 0.f;
        int cl = 1;
        if (isUpd) {
            cl = idx[ur * TT + t];
            const float* Gr = G + cl * 2048;
            gf  = Gr[h0 + uc];
            gi  = Gr[512 + h0 + uc];
            sgc = Gr[1536 + h0 + uc];
        }

        // ---- 2-col dot over 16 h', all 4 rows (2-way broadcast reads) ----
        // Cs holds C(t-1) (zeros at t == t0).
        float fA[RPG], fB[RPG], iA[RPG], iB[RPG];
        #pragma unroll
        for (int r = 0; r < RPG; ++r) { fA[r] = 0.f; fB[r] = 0.f; iA[r] = 0.f; iB[r] = 0.f; }
        {
            const int cb4 = chunk * 4;    // float4 index of chunk base
            #pragma unroll
            for (int j = 0; j < 4; ++j) {
                const float a0 = wfA[4*j], a1 = wfA[4*j+1], a2 = wfA[4*j+2], a3 = wfA[4*j+3];
                const float b0 = wfB[4*j], b1 = wfB[4*j+1], b2 = wfB[4*j+2], b3 = wfB[4*j+3];
                const float c0 = wiA[4*j], c1 = wiA[4*j+1], c2 = wiA[4*j+2], c3 = wiA[4*j+3];
                const float d0 = wiB[4*j], d1 = wiB[4*j+1], d2 = wiB[4*j+2], d3 = wiB[4*j+3];
                #pragma unroll
                for (int r = 0; r < RPG; ++r) {
                    const float4 cv = reinterpret_cast<const float4*>(
                        Cs + r * CPAD)[cb4 + j];
                    fA[r] += a0*cv.x + a1*cv.y + a2*cv.z + a3*cv.w;
                    fB[r] += b0*cv.x + b1*cv.y + b2*cv.z + b3*cv.w;
                    iA[r] += c0*cv.x + c1*cv.y + c2*cv.z + c3*cv.w;
                    iB[r] += d0*cv.x + d1*cv.y + d2*cv.z + d3*cv.w;
                }
            }
        }
        {
            float2* ppA = part2 + (chunk * 64 + cp)      * PST;
            float2* ppB = part2 + (chunk * 64 + cp + 32) * PST;
            #pragma unroll
            for (int r = 0; r < RPG; ++r) {
                ppA[r] = make_float2(fA[r], iA[r]);
                ppB[r] = make_float2(fB[r], iB[r]);
            }
        }
        __syncthreads();                      // S1: partials ready, Cs fully read

        if (isUpd) {
            // ---- update: wave w == row w owns (col uc, row ur) ----
            float df = 0.f, di = 0.f;
            #pragma unroll
            for (int ch = 0; ch < 32; ++ch) {
                const float2 v = part2[(ch * 64 + uc) * PST + ur];
                df += v.x;
                di += v.y;
            }
            float Cn = sgc * sigf(gi + di) + Creg * sigf(gf + df);
            Cn = (cl > 0) ? Cn : 0.0f;
            Creg = Cn;
            if (!lastStep) {
                cst(&pub[(r0 + ur) * HD + h0 + uc], Cn);
                Cs[ur * CPAD + h0 + uc] = Cn;     // own slice staged locally
                // per-WAVE drain: this wave's 64 coherent stores are acked at
                // the coherence point before the flag below is issued.
                asm volatile("s_waitcnt vmcnt(0)" ::: "memory");
                if (uc == 0) cstu(&myf[ur], (unsigned)(t + 1));
            }
            // lastStep: nothing reads global C(T-1); keep Cs = C(T-2) for the
            // o-gate epilogue, Creg = C(T-1) for tanh.
        } else if (sw >= 8 && !lastStep) {
            // ---- stager wave: rank q's 64-col block, all 4 rows ----
            const int q = sw - 8;
            if (q != rank) {
                const unsigned* qf = flags + (grp * 8 + q) * 32;
                const unsigned tq = (unsigned)(t + 1);
                for (;;) {
                    const unsigned a = cldu(qf + 0), b = cldu(qf + 1);
                    const unsigned c = cldu(qf + 2), d = cldu(qf + 3);
                    if (a >= tq && b >= tq && c >= tq && d >= tq) break;
                }
                asm volatile("" ::: "memory");   // no hoisting of the loads below
                const float* src = pub + r0 * HD + q * COLS + sl;
                const float v0 = cld(src);
                const float v1 = cld(src + HD);
                const float v2 = cld(src + 2 * HD);
                const float v3 = cld(src + 3 * HD);
                Cs[0 * CPAD + q * COLS + sl] = v0;
                Cs[1 * CPAD + q * COLS + sl] = v1;
                Cs[2 * CPAD + q * COLS + sl] = v2;
                Cs[3 * CPAD + q * COLS + sl] = v3;
            }
        }
        __syncthreads();                      // S2: Cs = C(t) complete
    }

    // ---- o-gate + h once. o uses the carry C(T-2) — exactly what Cs still
    // holds, since the final step skipped staging. (t0==TT edge: Cs = 0 and
    // every row resets at T-1, so h = tanh(0)*o = 0 regardless.)
    {
        const int oc = tid & 63, och = tid >> 6;
        float ao[RPG];
        #pragma unroll
        for (int r = 0; r < RPG; ++r) ao[r] = 0.0f;
        #pragma unroll 4
        for (int k = 0; k < 32; ++k) {
            const int hp = och * 32 + k;
            const float wo = ldv<BF>(Woc, hp * HD + h0 + oc);
            #pragma unroll
            for (int r = 0; r < RPG; ++r)
                ao[r] += wo * Cs[r * CPAD + hp];
        }
        {
            float2* pp = part2 + (och * 64 + oc) * PST;
            #pragma unroll
            for (int r2 = 0; r2 < RPG / 2; ++r2)
                pp[r2] = make_float2(ao[2 * r2], ao[2 * r2 + 1]);
        }
        __syncthreads();
        if (isUpd) {
            float s = 0.f;
            #pragma unroll
            for (int ch = 0; ch < 16; ++ch) {
                const float2 v = part2[(ch * 64 + uc) * PST + (ur >> 1)];
                s += (ur & 1) ? v.y : v.x;
            }
            const int cl2 = idx[ur * TT + TT - 1];
            const float o = sigf(G[cl2 * 2048 + 1024 + h0 + uc] + s);
            Hfb[(r0 + ur) * HD + h0 + uc] = tanhf(Creg) * o;
        }
    }
}

// ---------------------------------------------------------------------------
// Projection + log_softmax, one WG per batch row.
// ---------------------------------------------------------------------------
template <bool BF>
__global__ __launch_bounds__(128) void proj(
    const int* __restrict__ flag, const float* __restrict__ Hfb,
    const void* __restrict__ Wph, const void* __restrict__ bp,
    void* __restrict__ out)
{
    if (*flag != (BF ? 1 : 0)) return;
    __shared__ __align__(16) float hv[HD];
    __shared__ float p_s[NCLS];
    __shared__ float lse_s;
    const int b   = blockIdx.x;
    const int tid = threadIdx.x;

    reinterpret_cast<float4*>(hv)[tid] =
        reinterpret_cast<const float4*>(Hfb + b * HD)[tid];
    __syncthreads();

    if (tid < NCLS) {
        float p = ldv<BF>(bp, tid);
        for (int h = 0; h < HD; ++h)
            p += hv[h] * ldv<BF>(Wph, h * NCLS + tid);
        p_s[tid] = p;
    }
    __syncthreads();
    if (tid == 0) {
        float m = -1e30f;
        for (int n = 0; n < NCLS; ++n) m = fmaxf(m, p_s[n]);
        float sum = 0.0f;
        for (int n = 0; n < NCLS; ++n) sum += expf(p_s[n] - m);
        lse_s = m + logf(sum);
    }
    __syncthreads();
    if (tid < NCLS) {
        const float v = p_s[tid] - lse_s;
        if constexpr (BF) ((bf16*)out)[b * NCLS + tid] = __float2bfloat16(v);
        else              ((float*)out)[b * NCLS + tid] = v;
    }
}

// ---------------------------------------------------------------------------
extern "C" void kernel_launch(void* const* d_in, const int* in_sizes, int n_in,
                              void* d_out, int out_size, void* d_ws, size_t ws_size,
                              hipStream_t stream) {
    const int*  x   = (const int*)d_in[0];
    const void* emb = d_in[1];
    const void* Wfx = d_in[2];
    const void* Wfc = d_in[3];
    const void* bfv = d_in[4];
    const void* Wix = d_in[5];
    const void* Wic = d_in[6];
    const void* biv = d_in[7];
    const void* Wox = d_in[8];
    const void* Woc = d_in[9];
    const void* bov = d_in[10];
    const void* Wcx = d_in[11];
    const void* bcv = d_in[12];
    const void* Wph = d_in[13];
    const void* bp  = d_in[14];

    int*      flag  = (int*)((char*)d_ws + WS_FLAG);
    unsigned* flags = (unsigned*)((char*)d_ws + WS_BAR);
    float*    G     = (float*)((char*)d_ws + WS_G);
    float*    C0    = (float*)((char*)d_ws + WS_C0);
    float*    C1    = (float*)((char*)d_ws + WS_C1);
    float*    Hfb   = (float*)((char*)d_ws + WS_HFB);

    init_k<<<1, 1024, 0, stream>>>((const uint32_t*)emb, flag, flags);

    build_G<false><<<dim3(NEMB, 8), 256, 0, stream>>>(flag, emb, Wfx, Wix, Wox, Wcx,
                                                      bfv, biv, bov, bcv, G);
    build_G<true ><<<dim3(NEMB, 8), 256, 0, stream>>>(flag, emb, Wfx, Wix, Wox, Wcx,
                                                      bfv, biv, bov, bcv, G);

    {
        void* args[] = {(void*)&flag, (void*)&x, (void*)&G,
                        (void*)&Wfc, (void*)&Wic, (void*)&Woc,
                        (void*)&C0, (void*)&C1, (void*)&Hfb, (void*)&flags};
        hipLaunchCooperativeKernel((const void*)recur_bs<false>, dim3(NGRP * GWG), dim3(THR),
                                   args, 0, stream);
        hipLaunchCooperativeKernel((const void*)recur_bs<true>, dim3(NGRP * GWG), dim3(THR),
                                   args, 0, stream);
    }

    proj<false><<<BB, 128, 0, stream>>>(flag, Hfb, Wph, bp, d_out);
    proj<true ><<<BB, 128, 0, stream>>>(flag, Hfb, Wph, bp, d_out);
}

// Round 2
// 1604.605 us; speedup vs baseline: 1.3348x; 1.3348x over previous
//
#include <hip/hip_runtime.h>
#include <hip/hip_bf16.h>
#include <stdint.h>

#define HD   512   // hidden dim H
#define ID   128   // input dim I
#define NCLS 100   // num classes
#define TT   512   // sequence length T
#define BB   128   // batch B
#define NEMB 101   // NC + 1 embedding rows
#define NGRP 32    // independent batch groups
#define GWG  8     // workgroups per group (sync clique)
#define RPG  4     // batch rows per group
#define COLS 64    // hidden cols per WG (GWG*COLS == HD)
#define THR  512   // threads per recurrence WG (8 waves, 2 waves/SIMD)
#define CPAD 640   // LDS C row stride in floats: 32 chunks x (16 data + 4 pad)
#define PST  5     // partials slot stride in float2 (4 rows + 1 pad)

// workspace layout (bytes)
#define WS_FLAG 0
#define WS_BAR  4096                   // u32 bars[NGRP*32] (128 B apart)
#define WS_G    65536                  // float G[101][2048]  (808 KB)
#define WS_C0   (1u * 1024 * 1024)     // float C0[128][512]  (256 KB)
#define WS_C1   (WS_C0 + 262144)       // float C1[128][512]  (256 KB)
#define WS_HFB  (WS_C1 + 262144)       // float Hfb[128][512] (256 KB)
#define NBARU   4096                   // u32s to zero

using bf16 = __hip_bfloat16;

__device__ __forceinline__ float b2f(bf16 v) { return __bfloat162float(v); }
__device__ __forceinline__ float sigf(float x) { return 1.0f / (1.0f + expf(-x)); }

// Agent-scope (sc1) accessors — proven r6-r17.
__device__ __forceinline__ float cld(const float* p) {
    return __hip_atomic_load(p, __ATOMIC_RELAXED, __HIP_MEMORY_SCOPE_AGENT);
}
__device__ __forceinline__ void cst(float* p, float v) {
    __hip_atomic_store(p, v, __ATOMIC_RELAXED, __HIP_MEMORY_SCOPE_AGENT);
}

template <bool BF>
__device__ __forceinline__ float ldv(const void* p, int i) {
    if constexpr (BF) return b2f(((const bf16*)p)[i]);
    else              return ((const float*)p)[i];
}

// padded Cs index for h' (16 data floats + 4 pad per chunk)
__device__ __forceinline__ int cpi(int h) { return (h >> 4) * 20 + (h & 15); }

// ---------------------------------------------------------------------------
// Group barrier — r13's best-measured flavor (RMW-IF + tight poll), restored
// after the r1 flag-exchange regression (2012 vs 1531 us: per-rank publish
// chain = drain + flag store + poll + dependent load is LONGER than one
// centralized RMW + parallel stage). Leading __syncthreads drains all waves'
// sc1 C stores before the arrive.
// ---------------------------------------------------------------------------
__device__ __forceinline__ void gbarrier(unsigned* cnt, unsigned* iter) {
    __syncthreads();
    if (threadIdx.x == 0) {
        __hip_atomic_fetch_add(cnt, 1u, __ATOMIC_RELAXED, __HIP_MEMORY_SCOPE_AGENT);
        const unsigned tgt = (*iter + 1u) * GWG;
        while (__hip_atomic_load(cnt, __ATOMIC_RELAXED, __HIP_MEMORY_SCOPE_AGENT) < tgt)
            ;
    }
    ++*iter;
    __syncthreads();
}

// ---------------------------------------------------------------------------
// Dtype sniffer + bars zeroing. emb row 0 is exactly 0.0 by construction:
// bytes [256,512) are zero iff f32 (row 0) and nonzero iff bf16 (row 1).
// ---------------------------------------------------------------------------
__global__ void init_k(const uint32_t* __restrict__ emb_raw,
                       int* __restrict__ flag, unsigned* __restrict__ bars) {
    const int t = threadIdx.x;
    for (int k = t; k < NBARU; k += 1024) bars[k] = 0u;
    if (t == 0) {
        uint32_t acc = 0;
        for (int i = 64; i < 128; ++i) acc |= emb_raw[i];
        *flag = (acc == 0u) ? 0 : 1;
    }
}

// ---------------------------------------------------------------------------
// G[c][j]: input-side gate pre-activations per class. j = q*512 + col,
// q in {0:f, 1:i, 2:o, 3:ctilde}; ctilde quarter pre-sigmoided.
// ---------------------------------------------------------------------------
template <bool BF>
__global__ void build_G(const int* __restrict__ flag,
                        const void* __restrict__ emb,
                        const void* __restrict__ Wfx, const void* __restrict__ Wix,
                        const void* __restrict__ Wox, const void* __restrict__ Wcx,
                        const void* __restrict__ bfv, const void* __restrict__ biv,
                        const void* __restrict__ bov, const void* __restrict__ bcv,
                        float* __restrict__ G) {
    if (*flag != (BF ? 1 : 0)) return;
    const int c   = blockIdx.x;
    const int j   = blockIdx.y * 256 + threadIdx.x;
    const int q   = j >> 9;
    const int col = j & 511;
    const void* W  = (q == 0) ? Wfx : (q == 1) ? Wix : (q == 2) ? Wox : Wcx;
    const void* bv = (q == 0) ? bfv : (q == 1) ? biv : (q == 2) ? bov : bcv;
    float acc = ldv<BF>(bv, col);
    for (int i = 0; i < ID; ++i)
        acc += ldv<BF>(emb, c * ID + i) * ldv<BF>(W, i * HD + col);
    if (q == 3) acc = sigf(acc);
    G[c * 2048 + j] = acc;
}

// ---------------------------------------------------------------------------
// Batch-split recurrence, 32 groups x 8 WGs x 64 cols — r13 sync structure
// (RMW-IF barrier), reshaped compute: 512 threads (8 waves) x 4 cols x 16 h'
// with 128 pinned weight regs. Each C float4 LDS read now feeds 32 FMAs
// (was 16): dot reads drop 256 -> 128 b128/CU/step, pushing the dot floor
// from the LDS pipe (~3072 cy) to the VALU (~2048 cy/SIMD, unchanged).
// Cs uses chunk stride 20 floats (16 data + 4 pad): the wave's 4 lane-groups
// (chunks +0..+3, 80 B apart) land on bank-quads {0,20,8,28} -> the 4-way
// read pattern is bank-conflict-free; float4 index is chunk*5 + j.
// Per step: [prefetch G] stage C(t) (4 sc1 loads/thread) -> sync -> dot
// (16 b128 reads, 512 FMA/thread) -> float2 partials (16 b64/thread) ->
// sync -> 256 update threads (gates, own C in Creg, sc1-store) -> 8-way
// barrier. Epilogue: o-gate dots Woc against C1 = C(T-1). Math and
// accumulation order identical to r13 -> bit-identical output.
// ---------------------------------------------------------------------------
template <bool BF>
__global__ __launch_bounds__(THR, 2) void recur_bs(
    const int* __restrict__ flag, const int* __restrict__ x,
    const float* __restrict__ G,
    const void* __restrict__ Wfc, const void* __restrict__ Wic,
    const void* __restrict__ Woc,
    float* __restrict__ C0, float* __restrict__ C1,
    float* __restrict__ Hfb, unsigned* __restrict__ bars)
{
    if (*flag != (BF ? 1 : 0)) return;

    __shared__ __align__(16) float Cs[RPG * CPAD];        // 10.2 KB
    __shared__ __align__(8)  float2 part2[2048 * PST];    // 80 KB
    __shared__ int idx[RPG * TT];                         // 8 KB
    __shared__ int lz[RPG];

    const int blk   = blockIdx.x;
    const int grp   = blk >> 3;           // 0..31
    const int rank  = blk & 7;            // 0..7
    const int r0    = grp * RPG;
    const int h0    = rank * COLS;
    const int tid   = threadIdx.x;
    const int cp    = tid & 15;           // col quad: cols cp, +16, +32, +48
    const int chunk = tid >> 4;           // 0..31 (16 h' each)
    unsigned* bar = bars + grp * 32;      // 128 B apart

    // ---- stage x rows (2048 ints, flat-contiguous), find group start ----
    idx[tid]        = x[r0 * TT + tid];
    idx[tid + 512]  = x[r0 * TT + tid + 512];
    idx[tid + 1024] = x[r0 * TT + tid + 1024];
    idx[tid + 1536] = x[r0 * TT + tid + 1536];
    if (tid < RPG) lz[tid] = -1;
    __syncthreads();
    #pragma unroll
    for (int r = 0; r < RPG; ++r)
        if (idx[r * TT + tid] == 0) atomicMax(&lz[r], tid);
    __syncthreads();
    int t0 = TT;
    #pragma unroll
    for (int r = 0; r < RPG; ++r) t0 = min(t0, lz[r] + 1);
    // t0 is group-uniform: every WG computes it from the same 4 rows.

    // ---- 128 pinned register weights: 4 cols x 2 gates x own 16-h' chunk --
    float wf0[16], wf1[16], wf2[16], wf3[16];
    float wi0[16], wi1[16], wi2[16], wi3[16];
    #pragma unroll
    for (int k = 0; k < 16; ++k) {
        const int hp = chunk * 16 + k;
        wf0[k] = ldv<BF>(Wfc, hp * HD + h0 + cp);
        wf1[k] = ldv<BF>(Wfc, hp * HD + h0 + cp + 16);
        wf2[k] = ldv<BF>(Wfc, hp * HD + h0 + cp + 32);
        wf3[k] = ldv<BF>(Wfc, hp * HD + h0 + cp + 48);
        wi0[k] = ldv<BF>(Wic, hp * HD + h0 + cp);
        wi1[k] = ldv<BF>(Wic, hp * HD + h0 + cp + 16);
        wi2[k] = ldv<BF>(Wic, hp * HD + h0 + cp + 32);
        wi3[k] = ldv<BF>(Wic, hp * HD + h0 + cp + 48);
    }
    #pragma unroll
    for (int k = 0; k < 16; ++k)
        asm volatile("" : "+v"(wf0[k]), "+v"(wf1[k]), "+v"(wf2[k]), "+v"(wf3[k]),
                          "+v"(wi0[k]), "+v"(wi1[k]), "+v"(wi2[k]), "+v"(wi3[k]));

    // ---- zero own C slices in both buffers (coherent stores) ----
    if (tid < COLS * RPG) {
        const int c = tid & 63, r = tid >> 6;
        cst(&C0[(r0 + r) * HD + h0 + c], 0.0f);
        cst(&C1[(r0 + r) * HD + h0 + c], 0.0f);
    }
    unsigned bi = 0;
    gbarrier(bar, &bi);                   // zeros visible group-wide

    float Creg = 0.0f;                    // update threads' own C element
    const bool isUpd = (tid < COLS * RPG);
    const int uc = tid & 63, ur = tid >> 6;   // update thread's (col, row)
    const int pe = cpi(tid);              // padded Cs index of col tid

    for (int t = t0; t < TT; ++t) {
        // re-pin the weights every iteration: forces them to stay VGPR-
        // resident through the loop body (the pre-loop pin alone was not
        // enough in r7/r8/r10 — allocator spilled after the asm point).
        #pragma unroll
        for (int k = 0; k < 16; ++k)
            asm volatile("" : "+v"(wf0[k]), "+v"(wf1[k]), "+v"(wf2[k]), "+v"(wf3[k]),
                              "+v"(wi0[k]), "+v"(wi1[k]), "+v"(wi2[k]), "+v"(wi3[k]));

        const float* cur = (t & 1) ? C1 : C0;
        float*       nxt = (t & 1) ? C0 : C1;

        // ---- prefetch G gate operands for the update (overlaps the stage)
        float gf = 0.f, gi = 0.f, sgc = 0.f;
        int cl = 1;
        if (isUpd) {
            cl = idx[ur * TT + t];
            const float* Gr = G + cl * 2048;
            gf  = Gr[h0 + uc];
            gi  = Gr[512 + h0 + uc];
            sgc = Gr[1536 + h0 + uc];
        }

        // ---- stage C(t): all 4 rows at h' = tid ----
        {
            const float v0 = cld(cur + (r0 + 0) * HD + tid);
            const float v1 = cld(cur + (r0 + 1) * HD + tid);
            const float v2 = cld(cur + (r0 + 2) * HD + tid);
            const float v3 = cld(cur + (r0 + 3) * HD + tid);
            Cs[0 * CPAD + pe] = v0;
            Cs[1 * CPAD + pe] = v1;
            Cs[2 * CPAD + pe] = v2;
            Cs[3 * CPAD + pe] = v3;
        }
        __syncthreads();

        // ---- 4-col dot over 16 h', all 4 rows (16-lane broadcast reads) ----
        float f0[RPG], f1[RPG], f2[RPG], f3[RPG];
        float i0[RPG], i1[RPG], i2[RPG], i3[RPG];
        #pragma unroll
        for (int r = 0; r < RPG; ++r) {
            f0[r] = 0.f; f1[r] = 0.f; f2[r] = 0.f; f3[r] = 0.f;
            i0[r] = 0.f; i1[r] = 0.f; i2[r] = 0.f; i3[r] = 0.f;
        }
        {
            const int cb = chunk * 5;     // float4 index of padded chunk base
            #pragma unroll
            for (int j = 0; j < 4; ++j) {
                #pragma unroll
                for (int r = 0; r < RPG; ++r) {
                    const float4 cv = reinterpret_cast<const float4*>(
                        Cs + r * CPAD)[cb + j];
                    f0[r] += wf0[4*j]*cv.x + wf0[4*j+1]*cv.y + wf0[4*j+2]*cv.z + wf0[4*j+3]*cv.w;
                    f1[r] += wf1[4*j]*cv.x + wf1[4*j+1]*cv.y + wf1[4*j+2]*cv.z + wf1[4*j+3]*cv.w;
                    f2[r] += wf2[4*j]*cv.x + wf2[4*j+1]*cv.y + wf2[4*j+2]*cv.z + wf2[4*j+3]*cv.w;
                    f3[r] += wf3[4*j]*cv.x + wf3[4*j+1]*cv.y + wf3[4*j+2]*cv.z + wf3[4*j+3]*cv.w;
                    i0[r] += wi0[4*j]*cv.x + wi0[4*j+1]*cv.y + wi0[4*j+2]*cv.z + wi0[4*j+3]*cv.w;
                    i1[r] += wi1[4*j]*cv.x + wi1[4*j+1]*cv.y + wi1[4*j+2]*cv.z + wi1[4*j+3]*cv.w;
                    i2[r] += wi2[4*j]*cv.x + wi2[4*j+1]*cv.y + wi2[4*j+2]*cv.z + wi2[4*j+3]*cv.w;
                    i3[r] += wi3[4*j]*cv.x + wi3[4*j+1]*cv.y + wi3[4*j+2]*cv.z + wi3[4*j+3]*cv.w;
                }
            }
        }
        {
            float2* p0 = part2 + (chunk * 64 + cp)      * PST;
            float2* p1 = part2 + (chunk * 64 + cp + 16) * PST;
            float2* p2 = part2 + (chunk * 64 + cp + 32) * PST;
            float2* p3 = part2 + (chunk * 64 + cp + 48) * PST;
            #pragma unroll
            for (int r = 0; r < RPG; ++r) {
                p0[r] = make_float2(f0[r], i0[r]);
                p1[r] = make_float2(f1[r], i1[r]);
                p2[r] = make_float2(f2[r], i2[r]);
                p3[r] = make_float2(f3[r], i3[r]);
            }
        }
        __syncthreads();

        // ---- update: thread t<256 owns (col = uc, row = ur) ----
        if (isUpd) {
            float df = 0.f, di = 0.f;
            #pragma unroll
            for (int ch = 0; ch < 32; ++ch) {
                const float2 v = part2[(ch * 64 + uc) * PST + ur];
                df += v.x;
                di += v.y;
            }
            float Cn = sgc * sigf(gi + di) + Creg * sigf(gf + df);
            Cn = (cl > 0) ? Cn : 0.0f;
            Creg = Cn;
            cst(&nxt[(r0 + ur) * HD + h0 + uc], Cn);
        }
        gbarrier(bar, &bi);
    }

    // ---- o-gate + h once. o uses C(T-1) = C1 (pre-update at final step;
    // TT-1 odd -> final input buffer is C1) --
    {
        const float v0 = cld(C1 + (r0 + 0) * HD + tid);
        const float v1 = cld(C1 + (r0 + 1) * HD + tid);
        const float v2 = cld(C1 + (r0 + 2) * HD + tid);
        const float v3 = cld(C1 + (r0 + 3) * HD + tid);
        Cs[0 * CPAD + pe] = v0;
        Cs[1 * CPAD + pe] = v1;
        Cs[2 * CPAD + pe] = v2;
        Cs[3 * CPAD + pe] = v3;
        __syncthreads();

        // thread = (oc = t&63 col, och = t>>6: 8 chunks x 64 h')
        const int oc = tid & 63, och = tid >> 6;
        float ao[RPG];
        #pragma unroll
        for (int r = 0; r < RPG; ++r) ao[r] = 0.0f;
        #pragma unroll 4
        for (int k = 0; k < 64; ++k) {
            const int hp = och * 64 + k;
            const int hpp = cpi(hp);
            const float wo = ldv<BF>(Woc, hp * HD + h0 + oc);
            #pragma unroll
            for (int r = 0; r < RPG; ++r)
                ao[r] += wo * Cs[r * CPAD + hpp];
        }
        {
            float2* pp = part2 + (och * 64 + oc) * PST;
            #pragma unroll
            for (int r2 = 0; r2 < RPG / 2; ++r2)
                pp[r2] = make_float2(ao[2 * r2], ao[2 * r2 + 1]);
        }
        __syncthreads();
        if (isUpd) {
            float s = 0.f;
            #pragma unroll
            for (int ch = 0; ch < 8; ++ch) {
                const float2 v = part2[(ch * 64 + uc) * PST + (ur >> 1)];
                s += (ur & 1) ? v.y : v.x;
            }
            const int cl2 = idx[ur * TT + TT - 1];
            const float o = sigf(G[cl2 * 2048 + 1024 + h0 + uc] + s);
            Hfb[(r0 + ur) * HD + h0 + uc] = tanhf(Creg) * o;
        }
    }
}

// ---------------------------------------------------------------------------
// Projection + log_softmax, one WG per batch row.
// ---------------------------------------------------------------------------
template <bool BF>
__global__ __launch_bounds__(128) void proj(
    const int* __restrict__ flag, const float* __restrict__ Hfb,
    const void* __restrict__ Wph, const void* __restrict__ bp,
    void* __restrict__ out)
{
    if (*flag != (BF ? 1 : 0)) return;
    __shared__ __align__(16) float hv[HD];
    __shared__ float p_s[NCLS];
    __shared__ float lse_s;
    const int b   = blockIdx.x;
    const int tid = threadIdx.x;

    reinterpret_cast<float4*>(hv)[tid] =
        reinterpret_cast<const float4*>(Hfb + b * HD)[tid];
    __syncthreads();

    if (tid < NCLS) {
        float p = ldv<BF>(bp, tid);
        for (int h = 0; h < HD; ++h)
            p += hv[h] * ldv<BF>(Wph, h * NCLS + tid);
        p_s[tid] = p;
    }
    __syncthreads();
    if (tid == 0) {
        float m = -1e30f;
        for (int n = 0; n < NCLS; ++n) m = fmaxf(m, p_s[n]);
        float sum = 0.0f;
        for (int n = 0; n < NCLS; ++n) sum += expf(p_s[n] - m);
        lse_s = m + logf(sum);
    }
    __syncthreads();
    if (tid < NCLS) {
        const float v = p_s[tid] - lse_s;
        if constexpr (BF) ((bf16*)out)[b * NCLS + tid] = __float2bfloat16(v);
        else              ((float*)out)[b * NCLS + tid] = v;
    }
}

// ---------------------------------------------------------------------------
extern "C" void kernel_launch(void* const* d_in, const int* in_sizes, int n_in,
                              void* d_out, int out_size, void* d_ws, size_t ws_size,
                              hipStream_t stream) {
    const int*  x   = (const int*)d_in[0];
    const void* emb = d_in[1];
    const void* Wfx = d_in[2];
    const void* Wfc = d_in[3];
    const void* bfv = d_in[4];
    const void* Wix = d_in[5];
    const void* Wic = d_in[6];
    const void* biv = d_in[7];
    const void* Wox = d_in[8];
    const void* Woc = d_in[9];
    const void* bov = d_in[10];
    const void* Wcx = d_in[11];
    const void* bcv = d_in[12];
    const void* Wph = d_in[13];
    const void* bp  = d_in[14];

    int*      flag = (int*)((char*)d_ws + WS_FLAG);
    unsigned* bars = (unsigned*)((char*)d_ws + WS_BAR);
    float*    G    = (float*)((char*)d_ws + WS_G);
    float*    C0   = (float*)((char*)d_ws + WS_C0);
    float*    C1   = (float*)((char*)d_ws + WS_C1);
    float*    Hfb  = (float*)((char*)d_ws + WS_HFB);

    init_k<<<1, 1024, 0, stream>>>((const uint32_t*)emb, flag, bars);

    build_G<false><<<dim3(NEMB, 8), 256, 0, stream>>>(flag, emb, Wfx, Wix, Wox, Wcx,
                                                      bfv, biv, bov, bcv, G);
    build_G<true ><<<dim3(NEMB, 8), 256, 0, stream>>>(flag, emb, Wfx, Wix, Wox, Wcx,
                                                      bfv, biv, bov, bcv, G);

    {
        void* args[] = {(void*)&flag, (void*)&x, (void*)&G,
                        (void*)&Wfc, (void*)&Wic, (void*)&Woc,
                        (void*)&C0, (void*)&C1, (void*)&Hfb, (void*)&bars};
        hipLaunchCooperativeKernel((const void*)recur_bs<false>, dim3(NGRP * GWG), dim3(THR),
                                   args, 0, stream);
        hipLaunchCooperativeKernel((const void*)recur_bs<true>, dim3(NGRP * GWG), dim3(THR),
                                   args, 0, stream);
    }

    proj<false><<<BB, 128, 0, stream>>>(flag, Hfb, Wph, bp, d_out);
    proj<true ><<<BB, 128, 0, stream>>>(flag, Hfb, Wph, bp, d_out);
}